// Round 2
// baseline (156.273 us; speedup 1.0000x reference)
//
#include <hip/hip_runtime.h>
#include <hip/hip_bf16.h>

typedef __attribute__((ext_vector_type(8))) short bf16x8;
typedef __attribute__((ext_vector_type(4))) float f32x4;
typedef unsigned short u16;
typedef unsigned int u32;

#define NP 34                                           // 32 + 2 halo
#define XT_BYTES ((size_t)4 * NP * NP * NP * 128 * 2)   // 40,247,296 B

__device__ __forceinline__ u16 f2bf(float f) {
  __hip_bfloat16 h = __float2bfloat16(f);
  return __builtin_bit_cast(u16, h);
}

__device__ __forceinline__ void gload_lds16(const u16* g, u16* l) {
  __builtin_amdgcn_global_load_lds(
      (const __attribute__((address_space(1))) u32*)g,
      (__attribute__((address_space(3))) u32*)l, 16, 0, 0);
}

#define WAITV(N) asm volatile("s_waitcnt vmcnt(" #N ")" ::: "memory")
#define BAR() do { __builtin_amdgcn_s_barrier(); asm volatile("" ::: "memory"); } while (0)

// ---------------- kernel 1: demod + modulated bf16 weights ----------------
// wmod[b][tap][oc][ic] = bf16( weight[oc][ic][tap] * y[b][ic] * demod[b][oc] )
__global__ __launch_bounds__(128) void kmodw(const float* __restrict__ w,
                                             const float* __restrict__ y,
                                             u16* __restrict__ wmod) {
  const int oc = blockIdx.x, b = blockIdx.y;
  const int ic = threadIdx.x;               // 128 threads
  const float* wp = w + (oc * 128 + ic) * 27;
  float wv[27];
  float s = 0.f;
#pragma unroll
  for (int t = 0; t < 27; ++t) { wv[t] = wp[t]; s += wv[t] * wv[t]; }
  const float yv = y[b * 128 + ic];
  float v = yv * yv * s;
#pragma unroll
  for (int m = 1; m < 64; m <<= 1) v += __shfl_xor(v, m);
  __shared__ float part[2];
  const int lane = ic & 63, wid = ic >> 6;
  if (lane == 0) part[wid] = v;
  __syncthreads();
  const float demod = rsqrtf(part[0] + part[1] + 1e-8f);
  const float sc = yv * demod;
#pragma unroll
  for (int t = 0; t < 27; ++t)
    wmod[((b * 27 + t) * 128 + oc) * 128 + ic] = f2bf(wv[t] * sc);
}

// ---------------- kernel 2: zero only the halo of xt ----------------------
__global__ __launch_bounds__(128) void khalo(u16* __restrict__ xt) {
  const int zy = blockIdx.x, b = blockIdx.y;
  const int zz = zy / NP, yy = zy % NP;
  u16* row = xt + ((size_t)((b * NP + zz) * NP + yy) * NP) * 128;
  u32* wp = (u32*)row;                      // 34*128 u16 = 2176 u32
  if (zz == 0 || zz == NP - 1 || yy == 0 || yy == NP - 1) {
#pragma unroll
    for (int i = 0; i < 17; ++i) wp[i * 128 + threadIdx.x] = 0;
  } else {
    if (threadIdx.x < 64) wp[threadIdx.x] = 0;
    else ((u32*)(row + 33 * 128))[threadIdx.x - 64] = 0;
  }
}

// ---------------- kernel 3: f32 -> bf16 transpose-cast (interior) ----------
__global__ __launch_bounds__(256) void kcastx(const float* __restrict__ x,
                                              u16* __restrict__ xt) {
  const int yq = blockIdx.x, z = blockIdx.y, b = blockIdx.z;
  const int tid = threadIdx.x;
  __shared__ u16 t[32 * 132];
  const float* xp = x + (size_t)b * 128 * 32768 + (z * 32 + yq) * 32;
#pragma unroll
  for (int p = 0; p < 16; ++p) {
    const int ic = p * 8 + (tid >> 5), xx = tid & 31;
    t[xx * 132 + ic] = f2bf(xp[(size_t)ic * 32768 + xx]);
  }
  __syncthreads();
  u16* xtb = xt + (((size_t)(b * NP + z + 1) * NP + (yq + 1)) * NP + 1) * 128;
#pragma unroll
  for (int p = 0; p < 4; ++p) {
    const int xx = p * 8 + (tid >> 5), icq = tid & 31;
    *(ushort4*)(xtb + (size_t)xx * 128 + icq * 4) = *(const ushort4*)&t[xx * 132 + icq * 4];
  }
}

// ---------------- kernel 4: pipelined implicit-GEMM conv ------------------
// Block: [128 oc][256 n] (8 y-rows x 32 x) at fixed (b,z). 8 waves (2x4).
// 54 half-K phases (27 taps x 2 ic-halves), A dbuf'd, B per-(dz,dy) halves,
// counted vmcnt (never drained in steady state), raw s_barrier.
__global__ __launch_bounds__(512, 2) void kconv(const u16* __restrict__ xt,
                                                const u16* __restrict__ wmod,
                                                float* __restrict__ out) {
  __shared__ __align__(16) u16 Alds[2][128 * 64];   // 32 KiB (dbuf, ic-half)
  __shared__ __align__(16) u16 B0[320 * 64];        // 40 KiB (ic 0..63),  rows yy*40+px
  __shared__ __align__(16) u16 B1[320 * 64];        // 40 KiB (ic 64..127)
  const int tid = threadIdx.x;
  const int lane = tid & 63, wid = tid >> 6;
  const int bsw = ((blockIdx.x & 7) << 6) + (blockIdx.x >> 3);  // XCD swizzle (512%8==0)
  const int yt = bsw & 3, z = (bsw >> 2) & 31, b = bsw >> 7;
  const int y0 = yt << 3;
  const int wm = wid >> 2, wn = wid & 3;            // 2(oc) x 4(n) wave grid

  const u16* xb = xt + (size_t)b * (NP * NP * NP) * 128;
  const u16* wb = wmod + (size_t)b * 27 * 16384;

  f32x4 acc[4][4];
#pragma unroll
  for (int i = 0; i < 4; ++i)
#pragma unroll
    for (int j = 0; j < 4; ++j) acc[i][j] = (f32x4){0.f, 0.f, 0.f, 0.f};

  // stage one A half-tile: [128 oc][64 ic] = 1024 slots = 2 rounds
  auto stageA = [&](int tap, int hb) {
    const u16* base = wb + tap * 16384 + hb * 64;
#pragma unroll
    for (int k = 0; k < 2; ++k) {
      const int s = (k << 9) + tid;
      const int oc = s >> 3, j = s & 7;
      gload_lds16(base + oc * 128 + ((j ^ (oc & 7)) << 3),
                  &Alds[hb][((k << 9) + (wid << 6)) << 3]);
    }
  };
  // stage one B half: [320 rows = 8yy x 40px][64 ic] = 2560 slots = 5 rounds
  auto stageB = [&](u16* Bh, int hb, int g) {
    const int dz = g / 3 - 1, dy = g % 3 - 1;
    const int pz = z + 1 + dz;
#pragma unroll
    for (int k = 0; k < 5; ++k) {
      const int s = (k << 9) + tid;
      const int r = s >> 3, j = s & 7;
      const int yy = r / 40;
      int px = r - yy * 40;
      px = px < 34 ? px : 33;                        // pad rows clamp (never read)
      const u16* src = xb + ((size_t)(pz * NP + (y0 + yy + 1 + dy)) * NP + px) * 128 +
                       hb * 64 + ((j ^ (r & 7)) << 3);
      gload_lds16(src, Bh + (((k << 9) + (wid << 6)) << 3));
    }
  };
  // one half-K compute phase: 16 ds_read_b128 + 32 MFMA per wave
  auto compute = [&](int hb, const u16* Bh, int dxi) {
    const u16* Ah = Alds[hb];
#pragma unroll
    for (int kk = 0; kk < 2; ++kk) {
      const int sg = (kk << 2) + (lane >> 4);
      bf16x8 af[4], bv[4];
#pragma unroll
      for (int m = 0; m < 4; ++m) {
        const int row = (wm << 6) + (m << 4) + (lane & 15);
        af[m] = *(const bf16x8*)&Ah[(row << 6) + ((sg ^ (row & 7)) << 3)];
      }
#pragma unroll
      for (int n = 0; n < 4; ++n) {
        const int nn = (wn << 6) + (n << 4) + (lane & 15);
        const int r = (nn >> 5) * 40 + (nn & 31) + dxi;
        bv[n] = *(const bf16x8*)&Bh[(r << 6) + ((sg ^ (r & 7)) << 3)];
      }
      __builtin_amdgcn_s_setprio(1);
#pragma unroll
      for (int m = 0; m < 4; ++m)
#pragma unroll
        for (int n = 0; n < 4; ++n)
          acc[m][n] = __builtin_amdgcn_mfma_f32_16x16x32_bf16(af[m], bv[n],
                                                              acc[m][n], 0, 0, 0);
      __builtin_amdgcn_s_setprio(0);
    }
  };

  // prologue: A(phase0) + B0(group0)
  stageA(0, 0);
  stageB(B0, 0, 0);

  for (int g = 0; g < 9; ++g) {
    const int tap = g * 3;
    // phase (dx=0, h=0) — group start
    stageB(B1, 1, g);
    stageA(tap, 1);
    WAITV(7); BAR();
    compute(0, B0, 0);
    BAR();
    // (0,1)
    stageA(tap + 1, 0);
    WAITV(2); BAR();
    compute(1, B1, 0);
    BAR();
    // (1,0)
    stageA(tap + 1, 1);
    WAITV(2); BAR();
    compute(0, B0, 1);
    BAR();
    // (1,1)
    stageA(tap + 2, 0);
    WAITV(2); BAR();
    compute(1, B1, 1);
    BAR();
    // (2,0)
    stageA(tap + 2, 1);
    WAITV(2); BAR();
    compute(0, B0, 2);
    BAR();
    // (2,1) — prefetch next group's A + B-half0
    if (g < 8) {
      stageA(tap + 3, 0);
      stageB(B0, 0, g + 1);
      WAITV(7); BAR();
      compute(1, B1, 2);
      BAR();
    } else {
      WAITV(0); BAR();
      compute(1, B1, 2);
      BAR();
    }
  }

  // epilogue: C/D layout col=lane&15, row=(lane>>4)*4+reg
  const int col = lane & 15, rg = lane >> 4;
#pragma unroll
  for (int m = 0; m < 4; ++m) {
    const int ocb = (wm << 6) + (m << 4) + (rg << 2);
#pragma unroll
    for (int n = 0; n < 4; ++n) {
      const int nn = (wn << 6) + (n << 4) + col;
      const int yy = nn >> 5, xx = nn & 31;
      float* op = out + ((size_t)(b * 128 + ocb) << 15) + (z << 10) +
                  ((y0 + yy) << 5) + xx;
#pragma unroll
      for (int r = 0; r < 4; ++r) op[(size_t)r << 15] = acc[m][n][r];
    }
  }
}

extern "C" void kernel_launch(void* const* d_in, const int* in_sizes, int n_in,
                              void* d_out, int out_size, void* d_ws, size_t ws_size,
                              hipStream_t stream) {
  const float* x = (const float*)d_in[0];
  const float* y = (const float*)d_in[1];
  const float* w = (const float*)d_in[2];
  float* out = (float*)d_out;
  u16* xt = (u16*)d_ws;
  u16* wmod = (u16*)((char*)d_ws + XT_BYTES);

  hipLaunchKernelGGL(khalo, dim3(NP * NP, 4), dim3(128), 0, stream, xt);
  hipLaunchKernelGGL(kmodw, dim3(128, 4), dim3(128), 0, stream, w, y, wmod);
  hipLaunchKernelGGL(kcastx, dim3(32, 32, 4), dim3(256), 0, stream, x, xt);
  hipLaunchKernelGGL(kconv, dim3(512), dim3(512), 0, stream, xt, wmod, out);
}

// Round 3
// 144.235 us; speedup vs baseline: 1.0835x; 1.0835x over previous
//
#include <hip/hip_runtime.h>
#include <hip/hip_bf16.h>

typedef __attribute__((ext_vector_type(8))) short bf16x8;
typedef __attribute__((ext_vector_type(4))) float f32x4;
typedef unsigned short u16;
typedef unsigned int u32;

#define NP 34                                           // 32 + 2 halo
#define XT_BYTES ((size_t)4 * NP * NP * NP * 128 * 2)   // 40,247,296 B

__device__ __forceinline__ u16 f2bf(float f) {
  __hip_bfloat16 h = __float2bfloat16(f);
  return __builtin_bit_cast(u16, h);
}

__device__ __forceinline__ void gload_lds16(const u16* g, u16* l) {
  __builtin_amdgcn_global_load_lds(
      (const __attribute__((address_space(1))) u32*)g,
      (__attribute__((address_space(3))) u32*)l, 16, 0, 0);
}

#define WAITV(N) asm volatile("s_waitcnt vmcnt(" #N ")" ::: "memory")
#define BAR() do { __builtin_amdgcn_s_barrier(); asm volatile("" ::: "memory"); } while (0)

// ---------------- kernel 1: demod + modulated bf16 weights ----------------
__global__ __launch_bounds__(128) void kmodw(const float* __restrict__ w,
                                             const float* __restrict__ y,
                                             u16* __restrict__ wmod) {
  const int oc = blockIdx.x, b = blockIdx.y;
  const int ic = threadIdx.x;               // 128 threads
  const float* wp = w + (oc * 128 + ic) * 27;
  float wv[27];
  float s = 0.f;
#pragma unroll
  for (int t = 0; t < 27; ++t) { wv[t] = wp[t]; s += wv[t] * wv[t]; }
  const float yv = y[b * 128 + ic];
  float v = yv * yv * s;
#pragma unroll
  for (int m = 1; m < 64; m <<= 1) v += __shfl_xor(v, m);
  __shared__ float part[2];
  const int lane = ic & 63, wid = ic >> 6;
  if (lane == 0) part[wid] = v;
  __syncthreads();
  const float demod = rsqrtf(part[0] + part[1] + 1e-8f);
  const float sc = yv * demod;
#pragma unroll
  for (int t = 0; t < 27; ++t)
    wmod[((b * 27 + t) * 128 + oc) * 128 + ic] = f2bf(wv[t] * sc);
}

// ---------------- kernel 2: zero only the halo of xt ----------------------
__global__ __launch_bounds__(128) void khalo(u16* __restrict__ xt) {
  const int zy = blockIdx.x, b = blockIdx.y;
  const int zz = zy / NP, yy = zy % NP;
  u16* row = xt + ((size_t)((b * NP + zz) * NP + yy) * NP) * 128;
  u32* wp = (u32*)row;
  if (zz == 0 || zz == NP - 1 || yy == 0 || yy == NP - 1) {
#pragma unroll
    for (int i = 0; i < 17; ++i) wp[i * 128 + threadIdx.x] = 0;
  } else {
    if (threadIdx.x < 64) wp[threadIdx.x] = 0;
    else ((u32*)(row + 33 * 128))[threadIdx.x - 64] = 0;
  }
}

// ---------------- kernel 3: f32 -> bf16 transpose-cast (interior) ----------
__global__ __launch_bounds__(256) void kcastx(const float* __restrict__ x,
                                              u16* __restrict__ xt) {
  const int yq = blockIdx.x, z = blockIdx.y, b = blockIdx.z;
  const int tid = threadIdx.x;
  __shared__ u16 t[32 * 132];
  const float* xp = x + (size_t)b * 128 * 32768 + (z * 32 + yq) * 32;
#pragma unroll
  for (int p = 0; p < 16; ++p) {
    const int ic = p * 8 + (tid >> 5), xx = tid & 31;
    t[xx * 132 + ic] = f2bf(xp[(size_t)ic * 32768 + xx]);
  }
  __syncthreads();
  u16* xtb = xt + (((size_t)(b * NP + z + 1) * NP + (yq + 1)) * NP + 1) * 128;
#pragma unroll
  for (int p = 0; p < 4; ++p) {
    const int xx = p * 8 + (tid >> 5), icq = tid & 31;
    *(ushort4*)(xtb + (size_t)xx * 128 + icq * 4) = *(const ushort4*)&t[xx * 132 + icq * 4];
  }
}

// ---------------- kernel 4: pipelined implicit-GEMM conv ------------------
// Block: [128 oc][128 n] (4 y-rows x 32 x) at fixed (b,z). 4 waves (2x2).
// Per (dz,dy) group: B staged once (2 ic-half planes, 40-px rows, dx by
// column offset); A ic-half double-buffered; 6 phases/group, counted vmcnt.
__global__ __launch_bounds__(256, 2) void kconv(const u16* __restrict__ xt,
                                                const u16* __restrict__ wmod,
                                                float* __restrict__ out) {
  __shared__ __align__(16) u16 Alds[2][128 * 64];   // 2 x 16 KiB
  __shared__ __align__(16) u16 Blds[2][160 * 64];   // 2 x 20 KiB
  const int tid = threadIdx.x;
  const int lane = tid & 63, wid = tid >> 6;
  const int bsw = ((blockIdx.x & 7) << 7) + (blockIdx.x >> 3);  // XCD swizzle
  const int yt = bsw & 7, z = (bsw >> 3) & 31, b = bsw >> 8;
  const int y0 = yt << 2;
  const int wm = wid >> 1, wn = wid & 1;            // 2(oc) x 2(n) wave grid

  const u16* xb = xt + (size_t)b * (NP * NP * NP) * 128;
  const u16* wb = wmod + (size_t)b * 27 * 16384;

  f32x4 acc[4][4];
#pragma unroll
  for (int i = 0; i < 4; ++i)
#pragma unroll
    for (int j = 0; j < 4; ++j) acc[i][j] = (f32x4){0.f, 0.f, 0.f, 0.f};

  // stage A ic-half: [128 oc][64 ic] = 1024 slots = 4 rounds of 256
  auto stageA = [&](int tap, int h) {
    const u16* base = wb + tap * 16384 + (h << 6);
#pragma unroll
    for (int k = 0; k < 4; ++k) {
      const int s = (k << 8) + tid;
      const int oc = s >> 3, j = s & 7;
      gload_lds16(base + (oc << 7) + ((j ^ (oc & 7)) << 3),
                  &Alds[h][((k << 8) + (wid << 6)) << 3]);
    }
  };
  // stage B group: 2 half-planes of [160 rows = 4yy x 40px][64 ic], 5 rounds each
  auto stageB = [&](int g) {
    const int dz = g / 3 - 1, dy = g % 3 - 1;
    const int pz = z + 1 + dz;
#pragma unroll
    for (int k = 0; k < 10; ++k) {
      const int h = (k >= 5) ? 1 : 0;
      const int k5 = (k >= 5) ? (k - 5) : k;
      const int s = (k5 << 8) + tid;
      const int r = s >> 3, j = s & 7;
      const int yy = r / 40;
      int px = r - yy * 40;
      px = px < 34 ? px : 33;                        // pad rows, never read
      const int py = y0 + yy + 1 + dy;
      gload_lds16(xb + ((size_t)(pz * NP + py) * NP + px) * 128 + (h << 6) +
                      ((j ^ (r & 7)) << 3),
                  &Blds[h][((k5 << 8) + (wid << 6)) << 3]);
    }
  };

#define COMPHALF(H, DXI)                                                     \
  {                                                                          \
    const u16* Ah = &Alds[H][0];                                             \
    const u16* Bh = &Blds[H][0];                                             \
    _Pragma("unroll") for (int kk = 0; kk < 2; ++kk) {                       \
      const int sg = (kk << 2) + (lane >> 4);                                \
      bf16x8 af[4], bv[4];                                                   \
      _Pragma("unroll") for (int m = 0; m < 4; ++m) {                        \
        const int row = (wm << 6) + (m << 4) + (lane & 15);                  \
        af[m] = *(const bf16x8*)&Ah[(row << 6) + ((sg ^ (row & 7)) << 3)];   \
      }                                                                      \
      _Pragma("unroll") for (int n = 0; n < 4; ++n) {                        \
        const int nn = (wn << 6) + (n << 4) + (lane & 15);                   \
        const int r = ((nn >> 5) * 40) + (nn & 31) + (DXI);                  \
        bv[n] = *(const bf16x8*)&Bh[(r << 6) + ((sg ^ (r & 7)) << 3)];       \
      }                                                                      \
      __builtin_amdgcn_s_setprio(1);                                         \
      _Pragma("unroll") for (int m = 0; m < 4; ++m)                          \
        _Pragma("unroll") for (int n = 0; n < 4; ++n)                        \
          acc[m][n] = __builtin_amdgcn_mfma_f32_16x16x32_bf16(               \
              af[m], bv[n], acc[m][n], 0, 0, 0);                             \
      __builtin_amdgcn_s_setprio(0);                                         \
    }                                                                        \
  }

  // prologue: B(g0) [10 loads], A(tap0,h0) [4], A(tap0,h1) [4]
  stageB(0);
  stageA(0, 0);
  stageA(0, 1);

  for (int g = 0; g < 9; ++g) {
    const int t = g * 3;
    // p0: (tap t, h0, dx=-1)
    WAITV(4); BAR(); COMPHALF(0, 0); BAR(); stageA(t + 1, 0);
    // p1: (t, h1, dx=-1)
    WAITV(4); BAR(); COMPHALF(1, 0); BAR(); stageA(t + 1, 1);
    // p2: (t+1, h0, dx=0)
    WAITV(4); BAR(); COMPHALF(0, 1); BAR(); stageA(t + 2, 0);
    // p3: (t+1, h1, dx=0)
    WAITV(4); BAR(); COMPHALF(1, 1); BAR(); stageA(t + 2, 1);
    // p4: (t+2, h0, dx=+1)
    WAITV(4); BAR(); COMPHALF(0, 2); BAR();
    if (g < 8) stageA(t + 3, 0);
    // p5: (t+2, h1, dx=+1) — group end: stage next B then next A-half
    if (g < 8) {
      WAITV(4); BAR(); COMPHALF(1, 2); BAR();
      stageB(g + 1);
      stageA(t + 3, 1);
    } else {
      WAITV(0); BAR(); COMPHALF(1, 2);
    }
  }

  // epilogue: C/D layout col=lane&15, row=(lane>>4)*4+reg
  const int col = lane & 15, rg = lane >> 4;
#pragma unroll
  for (int m = 0; m < 4; ++m) {
    const int ocb = (wm << 6) + (m << 4) + (rg << 2);
#pragma unroll
    for (int n = 0; n < 4; ++n) {
      const int nn = (wn << 6) + (n << 4) + col;
      const int yy = nn >> 5, xx = nn & 31;
      float* op = out + ((size_t)(b * 128 + ocb) << 15) + (z << 10) +
                  ((y0 + yy) << 5) + xx;
#pragma unroll
      for (int r = 0; r < 4; ++r) op[(size_t)r << 15] = acc[m][n][r];
    }
  }
#undef COMPHALF
}

extern "C" void kernel_launch(void* const* d_in, const int* in_sizes, int n_in,
                              void* d_out, int out_size, void* d_ws, size_t ws_size,
                              hipStream_t stream) {
  const float* x = (const float*)d_in[0];
  const float* y = (const float*)d_in[1];
  const float* w = (const float*)d_in[2];
  float* out = (float*)d_out;
  u16* xt = (u16*)d_ws;
  u16* wmod = (u16*)((char*)d_ws + XT_BYTES);

  hipLaunchKernelGGL(khalo, dim3(NP * NP, 4), dim3(128), 0, stream, xt);
  hipLaunchKernelGGL(kmodw, dim3(128, 4), dim3(128), 0, stream, w, y, wmod);
  hipLaunchKernelGGL(kcastx, dim3(32, 32, 4), dim3(256), 0, stream, x, xt);
  hipLaunchKernelGGL(kconv, dim3(1024), dim3(256), 0, stream, xt, wmod, out);
}